// Round 1
// baseline (671.586 us; speedup 1.0000x reference)
//
#include <hip/hip_runtime.h>
#include <stdint.h>

#define Bb 8
#define Nn 256
#define Hh 768
#define Pp 128
#define HEADS 12
#define Dd 64
#define EPSf 1e-5f

typedef __attribute__((ext_vector_type(8))) short bhalf8;   // 8 bf16 (4 VGPRs)
typedef __attribute__((ext_vector_type(4))) float f32x4;

__device__ __forceinline__ unsigned short f2bf(float f) {
    union { float f; unsigned u; } v; v.f = f;
    unsigned r = v.u + 0x7FFFu + ((v.u >> 16) & 1u);
    return (unsigned short)(r >> 16);
}
__device__ __forceinline__ float bflo(unsigned u) {
    union { unsigned u; float f; } v; v.u = u << 16; return v.f;
}
__device__ __forceinline__ float bfhi(unsigned u) {
    union { unsigned u; float f; } v; v.u = u & 0xFFFF0000u; return v.f;
}

// ---------------- K0: transpose fp32 [R][C] -> bf16 out[c*R + r] ----------------
__global__ __launch_bounds__(256) void k_transpose_bf16(const float* __restrict__ in,
                                                        unsigned short* __restrict__ out,
                                                        int R, int C) {
    __shared__ float tile[32][33];
    int c0 = blockIdx.x * 32, r0 = blockIdx.y * 32;
    int tx = threadIdx.x & 31, ty = threadIdx.x >> 5;  // ty in 0..7
    for (int i = ty; i < 32; i += 8) {
        int r = r0 + i, c = c0 + tx;
        tile[i][tx] = (r < R && c < C) ? in[(size_t)r * C + c] : 0.f;
    }
    __syncthreads();
    for (int i = ty; i < 32; i += 8) {
        int c = c0 + i, r = r0 + tx;
        if (c < C && r < R) out[(size_t)c * R + r] = f2bf(tile[tx][i]);
    }
}

// ---------------- K1: QKV projection, MFMA bf16 ----------------
// C[2048,2304] = nodes[2048,768] @ [Wq|Wk|Wv]; epilogue bias, q-scale, split layout
__global__ __launch_bounds__(256) void k_qkv(const float* __restrict__ nodes,
                                             const unsigned short* __restrict__ Wt, // [2304][768] n-major
                                             const float* __restrict__ bq, const float* __restrict__ bk,
                                             const float* __restrict__ bv,
                                             float* __restrict__ qs, float* __restrict__ kk,
                                             float* __restrict__ vv) {
    __shared__ __align__(16) unsigned short Alds[64 * 72];
    __shared__ __align__(16) unsigned short Blds[128 * 72];
    int tid = threadIdx.x;
    int m0 = blockIdx.y * 64;
    int n0 = blockIdx.x * 128;
    int w = tid >> 6, lane = tid & 63;
    int wm = w >> 1, wn = w & 1;
    int lm = lane & 15, lq = lane >> 4;
    f32x4 acc[2][4];
#pragma unroll
    for (int i = 0; i < 2; i++)
#pragma unroll
        for (int j = 0; j < 4; j++) acc[i][j] = (f32x4){0.f, 0.f, 0.f, 0.f};

    for (int kt = 0; kt < 768; kt += 64) {
#pragma unroll
        for (int t = 0; t < 4; t++) {  // A: 64x64 fp32 -> bf16
            int c = t * 256 + tid;
            int row = c >> 4, cc = c & 15;
            float4 v = *(const float4*)(nodes + (size_t)(m0 + row) * 768 + kt + cc * 4);
            unsigned u0 = (unsigned)f2bf(v.x) | ((unsigned)f2bf(v.y) << 16);
            unsigned u1 = (unsigned)f2bf(v.z) | ((unsigned)f2bf(v.w) << 16);
            uint2 uu; uu.x = u0; uu.y = u1;
            *(uint2*)(Alds + row * 72 + cc * 4) = uu;
        }
#pragma unroll
        for (int t = 0; t < 4; t++) {  // B: 128x64 bf16
            int c = t * 256 + tid;
            int n = c >> 3, kc = c & 7;
            uint4 v = *(const uint4*)(Wt + (size_t)(n0 + n) * 768 + kt + kc * 8);
            *(uint4*)(Blds + n * 72 + kc * 8) = v;
        }
        __syncthreads();
#pragma unroll
        for (int ks = 0; ks < 2; ks++) {
            bhalf8 af[2];
#pragma unroll
            for (int mi = 0; mi < 2; mi++)
                af[mi] = *(const bhalf8*)(Alds + (wm * 32 + mi * 16 + lm) * 72 + ks * 32 + lq * 8);
#pragma unroll
            for (int nt = 0; nt < 4; nt++) {
                bhalf8 bf = *(const bhalf8*)(Blds + (wn * 64 + nt * 16 + lm) * 72 + ks * 32 + lq * 8);
#pragma unroll
                for (int mi = 0; mi < 2; mi++)
                    acc[mi][nt] = __builtin_amdgcn_mfma_f32_16x16x32_bf16(af[mi], bf, acc[mi][nt], 0, 0, 0);
            }
        }
        __syncthreads();
    }
    int wsel = n0 / 768;
    int nb = n0 % 768;
    const float* bias = (wsel == 0) ? bq : (wsel == 1) ? bk : bv;
    float* dst = (wsel == 0) ? qs : (wsel == 1) ? kk : vv;
    float scale = (wsel == 0) ? 0.125f : 1.0f;
#pragma unroll
    for (int mi = 0; mi < 2; mi++)
#pragma unroll
        for (int nt = 0; nt < 4; nt++)
#pragma unroll
            for (int r = 0; r < 4; r++) {
                int row = m0 + wm * 32 + mi * 16 + lq * 4 + r;
                int col = nb + wn * 64 + nt * 16 + lm;
                int hh = col >> 6, d = col & 63;
                int b = row >> 8, qn = row & 255;
                float val = (acc[mi][nt][r] + bias[col]) * scale;
                dst[(((size_t)b * HEADS + hh) * Nn + qn) * Dd + d] = val;
            }
}

// ---------------- K2: content scores + bias, MFMA ----------------
// w[bh, 256, 256] = qs[bh] @ kk[bh]^T + bias
__global__ __launch_bounds__(256) void k_scores(const float* __restrict__ qs,
                                                const float* __restrict__ kk,
                                                const float* __restrict__ bias,
                                                float* __restrict__ wg) {
    __shared__ __align__(16) unsigned short Alds[64 * 72];
    __shared__ __align__(16) unsigned short Blds[64 * 72];
    int tid = threadIdx.x;
    int bh = blockIdx.z;
    int m0 = blockIdx.y * 64;
    int n0 = blockIdx.x * 64;
    int w = tid >> 6, lane = tid & 63, lm = lane & 15, lq = lane >> 4;
    const float* Abase = qs + ((size_t)bh * Nn + m0) * Dd;
    const float* Bbase = kk + ((size_t)bh * Nn + n0) * Dd;
#pragma unroll
    for (int t = 0; t < 4; t++) {
        int c = t * 256 + tid;
        int row = c >> 4, cc = c & 15;
        float4 va = *(const float4*)(Abase + (size_t)row * 64 + cc * 4);
        uint2 ua;
        ua.x = (unsigned)f2bf(va.x) | ((unsigned)f2bf(va.y) << 16);
        ua.y = (unsigned)f2bf(va.z) | ((unsigned)f2bf(va.w) << 16);
        *(uint2*)(Alds + row * 72 + cc * 4) = ua;
        float4 vb = *(const float4*)(Bbase + (size_t)row * 64 + cc * 4);
        uint2 ub;
        ub.x = (unsigned)f2bf(vb.x) | ((unsigned)f2bf(vb.y) << 16);
        ub.y = (unsigned)f2bf(vb.z) | ((unsigned)f2bf(vb.w) << 16);
        *(uint2*)(Blds + row * 72 + cc * 4) = ub;
    }
    __syncthreads();
    f32x4 acc[4];
#pragma unroll
    for (int i = 0; i < 4; i++) acc[i] = (f32x4){0.f, 0.f, 0.f, 0.f};
#pragma unroll
    for (int ks = 0; ks < 2; ks++) {
        bhalf8 af = *(const bhalf8*)(Alds + (w * 16 + lm) * 72 + ks * 32 + lq * 8);
#pragma unroll
        for (int nt = 0; nt < 4; nt++) {
            bhalf8 bf = *(const bhalf8*)(Blds + (nt * 16 + lm) * 72 + ks * 32 + lq * 8);
            acc[nt] = __builtin_amdgcn_mfma_f32_16x16x32_bf16(af, bf, acc[nt], 0, 0, 0);
        }
    }
#pragma unroll
    for (int nt = 0; nt < 4; nt++)
#pragma unroll
        for (int r = 0; r < 4; r++) {
            int row = m0 + w * 16 + lq * 4 + r;
            int col = n0 + nt * 16 + lm;
            size_t idx = ((size_t)bh * Nn + row) * Nn + col;
            wg[idx] = acc[nt][r] + bias[idx];
        }
}

// ---------------- K3: path LayerNorm + struct K/V projection, MFMA ----------------
// skv[r][0:64]=LN(paths[r])@Wsk+bsk ; skv[r][64:128]=...@Wsv+bsv  (bf16 out)
__global__ __launch_bounds__(256) void k_structproj(const float* __restrict__ paths,
                                                    const unsigned short* __restrict__ Wskvt, // [128][128] c-major
                                                    const float* __restrict__ gp, const float* __restrict__ bp,
                                                    const float* __restrict__ bsk, const float* __restrict__ bsv,
                                                    unsigned short* __restrict__ skv) {
    __shared__ __align__(16) unsigned short pn[64 * 136];
    __shared__ __align__(16) unsigned short Bt[128 * 136];
    int tid = threadIdx.x;
    size_t r0 = (size_t)blockIdx.x * 64;
    int w = tid >> 6, lane = tid & 63, lm = lane & 15, lq = lane >> 4;
#pragma unroll
    for (int t = 0; t < 8; t++) {  // stage Wskvt: 128x128 bf16
        int c = t * 256 + tid;
        int n = c >> 4, kc = c & 15;
        uint4 v = *(const uint4*)(Wskvt + n * 128 + kc * 8);
        *(uint4*)(Bt + n * 136 + kc * 8) = v;
    }
    float2 g2 = *(const float2*)(gp + lane * 2);
    float2 b2 = *(const float2*)(bp + lane * 2);
    float2 xr[16];
#pragma unroll
    for (int i = 0; i < 16; i++) {
        size_t row = r0 + w * 16 + i;
        xr[i] = *(const float2*)(paths + row * 128 + lane * 2);
    }
#pragma unroll
    for (int i = 0; i < 16; i++) {
        float2 x = xr[i];
        float s = x.x + x.y, s2 = x.x * x.x + x.y * x.y;
#pragma unroll
        for (int mk = 32; mk; mk >>= 1) {
            s += __shfl_xor(s, mk);
            s2 += __shfl_xor(s2, mk);
        }
        float mu = s * (1.f / 128.f);
        float var = s2 * (1.f / 128.f) - mu * mu;
        float rs = rsqrtf(var + EPSf);
        float p0 = (x.x - mu) * rs * g2.x + b2.x;
        float p1 = (x.y - mu) * rs * g2.y + b2.y;
        unsigned u = (unsigned)f2bf(p0) | ((unsigned)f2bf(p1) << 16);
        *(unsigned*)(pn + (w * 16 + i) * 136 + lane * 2) = u;
    }
    __syncthreads();
    f32x4 acc[8];
#pragma unroll
    for (int i = 0; i < 8; i++) acc[i] = (f32x4){0.f, 0.f, 0.f, 0.f};
#pragma unroll
    for (int ks = 0; ks < 4; ks++) {
        bhalf8 af = *(const bhalf8*)(pn + (w * 16 + lm) * 136 + ks * 32 + lq * 8);
#pragma unroll
        for (int nt = 0; nt < 8; nt++) {
            bhalf8 bf = *(const bhalf8*)(Bt + (nt * 16 + lm) * 136 + ks * 32 + lq * 8);
            acc[nt] = __builtin_amdgcn_mfma_f32_16x16x32_bf16(af, bf, acc[nt], 0, 0, 0);
        }
    }
#pragma unroll
    for (int nt = 0; nt < 8; nt++) {
        int col = nt * 16 + lm;
        float bias = (col < 64) ? bsk[col] : bsv[col - 64];
#pragma unroll
        for (int r = 0; r < 4; r++) {
            size_t grow = r0 + w * 16 + lq * 4 + r;
            skv[grow * 128 + col] = f2bf(acc[nt][r] + bias);
        }
    }
}

// ---------------- K4: per-(b,q) struct scores + softmax + struct-out ----------------
__global__ __launch_bounds__(256) void k_attn(const float* __restrict__ qs,
                                              const unsigned short* __restrict__ skv,
                                              float* __restrict__ wg,
                                              float* __restrict__ attn) {
    __shared__ __align__(16) unsigned skl[256 * 36];
    __shared__ __align__(16) float qv[12 * 64];
    __shared__ __align__(16) float wl[12 * 260];
    __shared__ float redm[4], reds[4];
    int tid = threadIdx.x;
    int bq = blockIdx.x;
    int b = bq >> 8, q = bq & 255;
    int lane = tid & 63, wid = tid >> 6;
#pragma unroll
    for (int i = 0; i < 3; i++) {
        int idx = i * 256 + tid;
        int h = idx >> 6, d = idx & 63;
        qv[idx] = qs[(((size_t)b * HEADS + h) * Nn + q) * Dd + d];
    }
    const unsigned short* rowb = skv + (size_t)bq * 256 * 128;
#pragma unroll
    for (int i = 0; i < 8; i++) {  // sk half
        int c = i * 256 + tid;
        int k = c >> 3, j = c & 7;
        uint4 v = *(const uint4*)(rowb + (size_t)k * 128 + j * 8);
        *(uint4*)(skl + k * 36 + j * 4) = v;
    }
    __syncthreads();
    for (int h = 0; h < 12; h++) {
        float s = 0.f;
#pragma unroll
        for (int j = 0; j < 32; j++) {
            unsigned u = skl[tid * 36 + j];
            float2 q2 = *(const float2*)(qv + h * 64 + 2 * j);
            s += q2.x * bflo(u) + q2.y * bfhi(u);
        }
        size_t widx = (((size_t)b * HEADS + h) * Nn + q) * Nn;
        s += wg[widx + tid];
        float m = s;
#pragma unroll
        for (int mk = 32; mk; mk >>= 1) m = fmaxf(m, __shfl_xor(m, mk));
        if (lane == 0) redm[wid] = m;
        __syncthreads();
        m = fmaxf(fmaxf(redm[0], redm[1]), fmaxf(redm[2], redm[3]));
        float p = __expf(s - m);
        float ps = p;
#pragma unroll
        for (int mk = 32; mk; mk >>= 1) ps += __shfl_xor(ps, mk);
        if (lane == 0) reds[wid] = ps;
        __syncthreads();
        float sum = reds[0] + reds[1] + reds[2] + reds[3];
        float pr = p / sum;
        wl[h * 260 + tid] = pr;
        wg[widx + tid] = pr;
        __syncthreads();
    }
#pragma unroll
    for (int i = 0; i < 8; i++) {  // sv half
        int c = i * 256 + tid;
        int k = c >> 3, j = c & 7;
        uint4 v = *(const uint4*)(rowb + (size_t)k * 128 + 64 + j * 8);
        *(uint4*)(skl + k * 36 + j * 4) = v;
    }
    __syncthreads();
#pragma unroll
    for (int i = 0; i < 3; i++) {
        int idx = i * 256 + tid;
        int h = idx >> 6, d = idx & 63;
        int jw = d >> 1;
        float o = 0.f;
        if (d & 1) {
            for (int k = 0; k < 256; k += 4) {
                float4 w4 = *(const float4*)(wl + h * 260 + k);
                o += w4.x * bfhi(skl[(k + 0) * 36 + jw]);
                o += w4.y * bfhi(skl[(k + 1) * 36 + jw]);
                o += w4.z * bfhi(skl[(k + 2) * 36 + jw]);
                o += w4.w * bfhi(skl[(k + 3) * 36 + jw]);
            }
        } else {
            for (int k = 0; k < 256; k += 4) {
                float4 w4 = *(const float4*)(wl + h * 260 + k);
                o += w4.x * bflo(skl[(k + 0) * 36 + jw]);
                o += w4.y * bflo(skl[(k + 1) * 36 + jw]);
                o += w4.z * bflo(skl[(k + 2) * 36 + jw]);
                o += w4.w * bflo(skl[(k + 3) * 36 + jw]);
            }
        }
        attn[(size_t)bq * Hh + idx] = o;
    }
}

// ---------------- K5: content out = softmax(w) @ V, accumulate into attn ----------------
__global__ __launch_bounds__(256) void k_ctxout(const float* __restrict__ wg,
                                                const float* __restrict__ vv,
                                                float* __restrict__ attn) {
    __shared__ __align__(16) float Al[64 * 68];
    __shared__ __align__(16) float Bl[64 * 68];
    int tid = threadIdx.x;
    int bh = blockIdx.y;
    int m0 = blockIdx.x * 64;
    int b = bh / 12, h = bh % 12;
    int tx = tid & 15, ty = tid >> 4;
    int c0 = tx * 4, r0 = ty * 4;
    float acc[4][4];
#pragma unroll
    for (int i = 0; i < 4; i++)
#pragma unroll
        for (int j = 0; j < 4; j++) acc[i][j] = 0.f;
    const float* Abase = wg + ((size_t)bh * Nn + m0) * Nn;
    const float* Bbase = vv + (size_t)bh * Nn * Dd;
    for (int kt = 0; kt < 256; kt += 64) {
#pragma unroll
        for (int t = 0; t < 4; t++) {
            int c = t * 256 + tid;
            int row = c >> 4, cc = c & 15;
            *(float4*)(Al + row * 68 + cc * 4) = *(const float4*)(Abase + (size_t)row * 256 + kt + cc * 4);
            *(float4*)(Bl + row * 68 + cc * 4) = *(const float4*)(Bbase + (size_t)(kt + row) * 64 + cc * 4);
        }
        __syncthreads();
#pragma unroll 8
        for (int k = 0; k < 64; k++) {
            float4 bv4 = *(const float4*)(Bl + k * 68 + c0);
            float a0 = Al[(r0 + 0) * 68 + k];
            float a1 = Al[(r0 + 1) * 68 + k];
            float a2 = Al[(r0 + 2) * 68 + k];
            float a3 = Al[(r0 + 3) * 68 + k];
            acc[0][0] += a0 * bv4.x; acc[0][1] += a0 * bv4.y; acc[0][2] += a0 * bv4.z; acc[0][3] += a0 * bv4.w;
            acc[1][0] += a1 * bv4.x; acc[1][1] += a1 * bv4.y; acc[1][2] += a1 * bv4.z; acc[1][3] += a1 * bv4.w;
            acc[2][0] += a2 * bv4.x; acc[2][1] += a2 * bv4.y; acc[2][2] += a2 * bv4.z; acc[2][3] += a2 * bv4.w;
            acc[3][0] += a3 * bv4.x; acc[3][1] += a3 * bv4.y; acc[3][2] += a3 * bv4.z; acc[3][3] += a3 * bv4.w;
        }
        __syncthreads();
    }
#pragma unroll
    for (int i = 0; i < 4; i++)
#pragma unroll
        for (int j = 0; j < 4; j++) {
            size_t o = ((size_t)b * Nn + m0 + r0 + i) * Hh + h * 64 + c0 + j;
            attn[o] += acc[i][j];
        }
}

// ---------------- K6: out projection + bias + relu + residual, MFMA ----------------
__global__ __launch_bounds__(256) void k_outproj(const float* __restrict__ attn,
                                                 const unsigned short* __restrict__ Wot, // [768][768] n-major
                                                 const float* __restrict__ bo,
                                                 const float* __restrict__ nodes,
                                                 float* __restrict__ tmp) {
    __shared__ __align__(16) unsigned short Alds[64 * 72];
    __shared__ __align__(16) unsigned short Blds[128 * 72];
    int tid = threadIdx.x;
    int m0 = blockIdx.y * 64;
    int n0 = blockIdx.x * 128;
    int w = tid >> 6, lane = tid & 63;
    int wm = w >> 1, wn = w & 1;
    int lm = lane & 15, lq = lane >> 4;
    f32x4 acc[2][4];
#pragma unroll
    for (int i = 0; i < 2; i++)
#pragma unroll
        for (int j = 0; j < 4; j++) acc[i][j] = (f32x4){0.f, 0.f, 0.f, 0.f};
    for (int kt = 0; kt < 768; kt += 64) {
#pragma unroll
        for (int t = 0; t < 4; t++) {
            int c = t * 256 + tid;
            int row = c >> 4, cc = c & 15;
            float4 v = *(const float4*)(attn + (size_t)(m0 + row) * 768 + kt + cc * 4);
            uint2 uu;
            uu.x = (unsigned)f2bf(v.x) | ((unsigned)f2bf(v.y) << 16);
            uu.y = (unsigned)f2bf(v.z) | ((unsigned)f2bf(v.w) << 16);
            *(uint2*)(Alds + row * 72 + cc * 4) = uu;
        }
#pragma unroll
        for (int t = 0; t < 4; t++) {
            int c = t * 256 + tid;
            int n = c >> 3, kc = c & 7;
            uint4 v = *(const uint4*)(Wot + (size_t)(n0 + n) * 768 + kt + kc * 8);
            *(uint4*)(Blds + n * 72 + kc * 8) = v;
        }
        __syncthreads();
#pragma unroll
        for (int ks = 0; ks < 2; ks++) {
            bhalf8 af[2];
#pragma unroll
            for (int mi = 0; mi < 2; mi++)
                af[mi] = *(const bhalf8*)(Alds + (wm * 32 + mi * 16 + lm) * 72 + ks * 32 + lq * 8);
#pragma unroll
            for (int nt = 0; nt < 4; nt++) {
                bhalf8 bf = *(const bhalf8*)(Blds + (wn * 64 + nt * 16 + lm) * 72 + ks * 32 + lq * 8);
#pragma unroll
                for (int mi = 0; mi < 2; mi++)
                    acc[mi][nt] = __builtin_amdgcn_mfma_f32_16x16x32_bf16(af[mi], bf, acc[mi][nt], 0, 0, 0);
            }
        }
        __syncthreads();
    }
#pragma unroll
    for (int mi = 0; mi < 2; mi++)
#pragma unroll
        for (int nt = 0; nt < 4; nt++)
#pragma unroll
            for (int r = 0; r < 4; r++) {
                int row = m0 + wm * 32 + mi * 16 + lq * 4 + r;
                int col = n0 + wn * 64 + nt * 16 + lm;
                float val = acc[mi][nt][r] + bo[col];
                val = fmaxf(val, 0.f) + nodes[(size_t)row * 768 + col];
                tmp[(size_t)row * 768 + col] = val;
            }
}

// ---------------- K7: final row LayerNorm ----------------
__global__ __launch_bounds__(256) void k_finalln(const float* __restrict__ tmp,
                                                 const float* __restrict__ go,
                                                 const float* __restrict__ bout,
                                                 float* __restrict__ out) {
    __shared__ float rs1[4], rs2[4];
    int m = blockIdx.x, tid = threadIdx.x;
    int lane = tid & 63, wid = tid >> 6;
    const float* row = tmp + (size_t)m * 768;
    float x0 = row[tid], x1 = row[tid + 256], x2 = row[tid + 512];
    float s = x0 + x1 + x2;
    float s2 = x0 * x0 + x1 * x1 + x2 * x2;
#pragma unroll
    for (int mk = 32; mk; mk >>= 1) {
        s += __shfl_xor(s, mk);
        s2 += __shfl_xor(s2, mk);
    }
    if (lane == 0) { rs1[wid] = s; rs2[wid] = s2; }
    __syncthreads();
    s = rs1[0] + rs1[1] + rs1[2] + rs1[3];
    s2 = rs2[0] + rs2[1] + rs2[2] + rs2[3];
    float mu = s * (1.f / 768.f);
    float var = s2 * (1.f / 768.f) - mu * mu;
    float rstd = rsqrtf(var + EPSf);
    float* orow = out + (size_t)m * 768;
    orow[tid] = (x0 - mu) * rstd * go[tid] + bout[tid];
    orow[tid + 256] = (x1 - mu) * rstd * go[tid + 256] + bout[tid + 256];
    orow[tid + 512] = (x2 - mu) * rstd * go[tid + 512] + bout[tid + 512];
}

extern "C" void kernel_launch(void* const* d_in, const int* in_sizes, int n_in,
                              void* d_out, int out_size, void* d_ws, size_t ws_size,
                              hipStream_t stream) {
    const float* nodes = (const float*)d_in[0];
    const float* bias  = (const float*)d_in[1];
    const float* paths = (const float*)d_in[2];
    const float* Wq = (const float*)d_in[3];  const float* bq  = (const float*)d_in[4];
    const float* Wk = (const float*)d_in[5];  const float* bk  = (const float*)d_in[6];
    const float* Wv = (const float*)d_in[7];  const float* bv  = (const float*)d_in[8];
    const float* Wsk = (const float*)d_in[9]; const float* bsk = (const float*)d_in[10];
    const float* Wsv = (const float*)d_in[11];const float* bsv = (const float*)d_in[12];
    const float* Wo = (const float*)d_in[13]; const float* bo  = (const float*)d_in[14];
    const float* gp = (const float*)d_in[15]; const float* bp  = (const float*)d_in[16];
    const float* go = (const float*)d_in[17]; const float* bout= (const float*)d_in[18];
    float* out = (float*)d_out;

    char* ws = (char*)d_ws;
    size_t off = 0;
    auto carve = [&](size_t bytes) -> char* {
        char* p = ws + off;
        off += (bytes + 255) & ~(size_t)255;
        return p;
    };
    float* qs   = (float*)carve((size_t)Bb * HEADS * Nn * Dd * 4);
    float* kk   = (float*)carve((size_t)Bb * HEADS * Nn * Dd * 4);
    float* vv   = (float*)carve((size_t)Bb * HEADS * Nn * Dd * 4);
    float* wg   = (float*)carve((size_t)Bb * HEADS * Nn * Nn * 4);
    float* attn = (float*)carve((size_t)Bb * Nn * Hh * 4);
    float* tmp  = (float*)carve((size_t)Bb * Nn * Hh * 4);
    unsigned short* Wqkvt = (unsigned short*)carve((size_t)3 * 768 * 768 * 2);
    unsigned short* Wot   = (unsigned short*)carve((size_t)768 * 768 * 2);
    unsigned short* Wskvt = (unsigned short*)carve((size_t)128 * 128 * 2);
    unsigned short* skv   = (unsigned short*)carve((size_t)Bb * Nn * Nn * 128 * 2);
    (void)ws_size; (void)in_sizes; (void)n_in; (void)out_size;

    // K0: weight transposes (fp32 -> bf16, n-major)
    hipLaunchKernelGGL(k_transpose_bf16, dim3(24, 24), dim3(256), 0, stream, Wq, Wqkvt, 768, 768);
    hipLaunchKernelGGL(k_transpose_bf16, dim3(24, 24), dim3(256), 0, stream, Wk, Wqkvt + (size_t)768 * 768, 768, 768);
    hipLaunchKernelGGL(k_transpose_bf16, dim3(24, 24), dim3(256), 0, stream, Wv, Wqkvt + (size_t)2 * 768 * 768, 768, 768);
    hipLaunchKernelGGL(k_transpose_bf16, dim3(24, 24), dim3(256), 0, stream, Wo, Wot, 768, 768);
    hipLaunchKernelGGL(k_transpose_bf16, dim3(2, 4), dim3(256), 0, stream, Wsk, Wskvt, 128, 64);
    hipLaunchKernelGGL(k_transpose_bf16, dim3(2, 4), dim3(256), 0, stream, Wsv, Wskvt + (size_t)64 * 128, 128, 64);

    // K1: QKV
    hipLaunchKernelGGL(k_qkv, dim3(18, 32), dim3(256), 0, stream, nodes, Wqkvt, bq, bk, bv, qs, kk, vv);
    // K2: content scores + bias
    hipLaunchKernelGGL(k_scores, dim3(4, 4, 96), dim3(256), 0, stream, qs, kk, bias, wg);
    // K3: path LN + struct projection
    hipLaunchKernelGGL(k_structproj, dim3(8192), dim3(256), 0, stream, paths, Wskvt, gp, bp, bsk, bsv, skv);
    // K4: struct scores + softmax + struct out
    hipLaunchKernelGGL(k_attn, dim3(2048), dim3(256), 0, stream, qs, skv, wg, attn);
    // K5: content out accumulate
    hipLaunchKernelGGL(k_ctxout, dim3(4, 96), dim3(256), 0, stream, wg, vv, attn);
    // K6: output projection + relu + residual
    hipLaunchKernelGGL(k_outproj, dim3(6, 32), dim3(256), 0, stream, attn, Wot, bo, nodes, tmp);
    // K7: final layernorm
    hipLaunchKernelGGL(k_finalln, dim3(2048), dim3(256), 0, stream, tmp, go, bout, out);
}

// Round 2
// 557.373 us; speedup vs baseline: 1.2049x; 1.2049x over previous
//
#include <hip/hip_runtime.h>
#include <stdint.h>

#define Bb 8
#define Nn 256
#define Hh 768
#define Pp 128
#define HEADS 12
#define Dd 64
#define EPSf 1e-5f

typedef __attribute__((ext_vector_type(8))) short bhalf8;   // 8 bf16 (4 VGPRs)
typedef __attribute__((ext_vector_type(4))) float f32x4;

__device__ __forceinline__ unsigned short f2bf(float f) {
    union { float f; unsigned u; } v; v.f = f;
    unsigned r = v.u + 0x7FFFu + ((v.u >> 16) & 1u);
    return (unsigned short)(r >> 16);
}

// ---------------- K0a: 4x transpose fp32 [768][768] -> bf16 n-major ----------------
__global__ __launch_bounds__(256) void k_transpose4(const float* __restrict__ a0, const float* __restrict__ a1,
                                                    const float* __restrict__ a2, const float* __restrict__ a3,
                                                    unsigned short* __restrict__ o0, unsigned short* __restrict__ o1,
                                                    unsigned short* __restrict__ o2, unsigned short* __restrict__ o3) {
    __shared__ float tile[32][33];
    int z = blockIdx.z;
    const float* in = (z == 0) ? a0 : (z == 1) ? a1 : (z == 2) ? a2 : a3;
    unsigned short* out = (z == 0) ? o0 : (z == 1) ? o1 : (z == 2) ? o2 : o3;
    const int R = 768, C = 768;
    int c0 = blockIdx.x * 32, r0 = blockIdx.y * 32;
    int tx = threadIdx.x & 31, ty = threadIdx.x >> 5;
    for (int i = ty; i < 32; i += 8)
        tile[i][tx] = in[(size_t)(r0 + i) * C + c0 + tx];
    __syncthreads();
    for (int i = ty; i < 32; i += 8)
        out[(size_t)(c0 + i) * R + r0 + tx] = f2bf(tile[tx][i]);
}

// ---------------- K0b: 2x transpose fp32 [128][64] -> bf16 [64][128] ----------------
__global__ __launch_bounds__(256) void k_transpose_small(const float* __restrict__ a0, const float* __restrict__ a1,
                                                         unsigned short* __restrict__ o0, unsigned short* __restrict__ o1) {
    __shared__ float tile[32][33];
    int z = blockIdx.z;
    const float* in = (z == 0) ? a0 : a1;
    unsigned short* out = (z == 0) ? o0 : o1;
    const int R = 128, C = 64;
    int c0 = blockIdx.x * 32, r0 = blockIdx.y * 32;
    int tx = threadIdx.x & 31, ty = threadIdx.x >> 5;
    for (int i = ty; i < 32; i += 8)
        tile[i][tx] = in[(size_t)(r0 + i) * C + c0 + tx];
    __syncthreads();
    for (int i = ty; i < 32; i += 8)
        out[(size_t)(c0 + i) * R + r0 + tx] = f2bf(tile[tx][i]);
}

// ---------------- K1: QKV projection, MFMA bf16 ----------------
__global__ __launch_bounds__(256) void k_qkv(const float* __restrict__ nodes,
                                             const unsigned short* __restrict__ Wt, // [2304][768] n-major
                                             const float* __restrict__ bq, const float* __restrict__ bk,
                                             const float* __restrict__ bv,
                                             float* __restrict__ qs, float* __restrict__ kk,
                                             float* __restrict__ vv) {
    __shared__ __align__(16) unsigned short Alds[64 * 72];
    __shared__ __align__(16) unsigned short Blds[128 * 72];
    int tid = threadIdx.x;
    int m0 = blockIdx.y * 64;
    int n0 = blockIdx.x * 128;
    int w = tid >> 6, lane = tid & 63;
    int wm = w >> 1, wn = w & 1;
    int lm = lane & 15, lq = lane >> 4;
    f32x4 acc[2][4];
#pragma unroll
    for (int i = 0; i < 2; i++)
#pragma unroll
        for (int j = 0; j < 4; j++) acc[i][j] = (f32x4){0.f, 0.f, 0.f, 0.f};

    for (int kt = 0; kt < 768; kt += 64) {
#pragma unroll
        for (int t = 0; t < 4; t++) {  // A: 64x64 fp32 -> bf16
            int c = t * 256 + tid;
            int row = c >> 4, cc = c & 15;
            float4 v = *(const float4*)(nodes + (size_t)(m0 + row) * 768 + kt + cc * 4);
            uint2 uu;
            uu.x = (unsigned)f2bf(v.x) | ((unsigned)f2bf(v.y) << 16);
            uu.y = (unsigned)f2bf(v.z) | ((unsigned)f2bf(v.w) << 16);
            *(uint2*)(Alds + row * 72 + cc * 4) = uu;
        }
#pragma unroll
        for (int t = 0; t < 4; t++) {  // B: 128x64 bf16
            int c = t * 256 + tid;
            int n = c >> 3, kc = c & 7;
            uint4 v = *(const uint4*)(Wt + (size_t)(n0 + n) * 768 + kt + kc * 8);
            *(uint4*)(Blds + n * 72 + kc * 8) = v;
        }
        __syncthreads();
#pragma unroll
        for (int ks = 0; ks < 2; ks++) {
            bhalf8 af[2];
#pragma unroll
            for (int mi = 0; mi < 2; mi++)
                af[mi] = *(const bhalf8*)(Alds + (wm * 32 + mi * 16 + lm) * 72 + ks * 32 + lq * 8);
#pragma unroll
            for (int nt = 0; nt < 4; nt++) {
                bhalf8 bf = *(const bhalf8*)(Blds + (wn * 64 + nt * 16 + lm) * 72 + ks * 32 + lq * 8);
#pragma unroll
                for (int mi = 0; mi < 2; mi++)
                    acc[mi][nt] = __builtin_amdgcn_mfma_f32_16x16x32_bf16(af[mi], bf, acc[mi][nt], 0, 0, 0);
            }
        }
        __syncthreads();
    }
    int wsel = n0 / 768;
    int nb = n0 % 768;
    const float* bias = (wsel == 0) ? bq : (wsel == 1) ? bk : bv;
    float* dst = (wsel == 0) ? qs : (wsel == 1) ? kk : vv;
    float scale = (wsel == 0) ? 0.125f : 1.0f;
#pragma unroll
    for (int mi = 0; mi < 2; mi++)
#pragma unroll
        for (int nt = 0; nt < 4; nt++)
#pragma unroll
            for (int r = 0; r < 4; r++) {
                int row = m0 + wm * 32 + mi * 16 + lq * 4 + r;
                int col = nb + wn * 64 + nt * 16 + lm;
                int hh = col >> 6, d = col & 63;
                int b = row >> 8, qn = row & 255;
                float val = (acc[mi][nt][r] + bias[col]) * scale;
                dst[(((size_t)b * HEADS + hh) * Nn + qn) * Dd + d] = val;
            }
}

// ---------------- K2: content scores + bias, MFMA ----------------
__global__ __launch_bounds__(256) void k_scores(const float* __restrict__ qs,
                                                const float* __restrict__ kk,
                                                const float* __restrict__ bias,
                                                float* __restrict__ wg) {
    __shared__ __align__(16) unsigned short Alds[64 * 72];
    __shared__ __align__(16) unsigned short Blds[64 * 72];
    int tid = threadIdx.x;
    int bh = blockIdx.z;
    int m0 = blockIdx.y * 64;
    int n0 = blockIdx.x * 64;
    int w = tid >> 6, lane = tid & 63, lm = lane & 15, lq = lane >> 4;
    const float* Abase = qs + ((size_t)bh * Nn + m0) * Dd;
    const float* Bbase = kk + ((size_t)bh * Nn + n0) * Dd;
#pragma unroll
    for (int t = 0; t < 4; t++) {
        int c = t * 256 + tid;
        int row = c >> 4, cc = c & 15;
        float4 va = *(const float4*)(Abase + (size_t)row * 64 + cc * 4);
        uint2 ua;
        ua.x = (unsigned)f2bf(va.x) | ((unsigned)f2bf(va.y) << 16);
        ua.y = (unsigned)f2bf(va.z) | ((unsigned)f2bf(va.w) << 16);
        *(uint2*)(Alds + row * 72 + cc * 4) = ua;
        float4 vb = *(const float4*)(Bbase + (size_t)row * 64 + cc * 4);
        uint2 ub;
        ub.x = (unsigned)f2bf(vb.x) | ((unsigned)f2bf(vb.y) << 16);
        ub.y = (unsigned)f2bf(vb.z) | ((unsigned)f2bf(vb.w) << 16);
        *(uint2*)(Blds + row * 72 + cc * 4) = ub;
    }
    __syncthreads();
    f32x4 acc[4];
#pragma unroll
    for (int i = 0; i < 4; i++) acc[i] = (f32x4){0.f, 0.f, 0.f, 0.f};
#pragma unroll
    for (int ks = 0; ks < 2; ks++) {
        bhalf8 af = *(const bhalf8*)(Alds + (w * 16 + lm) * 72 + ks * 32 + lq * 8);
#pragma unroll
        for (int nt = 0; nt < 4; nt++) {
            bhalf8 bf = *(const bhalf8*)(Blds + (nt * 16 + lm) * 72 + ks * 32 + lq * 8);
            acc[nt] = __builtin_amdgcn_mfma_f32_16x16x32_bf16(af, bf, acc[nt], 0, 0, 0);
        }
    }
#pragma unroll
    for (int nt = 0; nt < 4; nt++)
#pragma unroll
        for (int r = 0; r < 4; r++) {
            int row = m0 + w * 16 + lq * 4 + r;
            int col = n0 + nt * 16 + lm;
            size_t idx = ((size_t)bh * Nn + row) * Nn + col;
            wg[idx] = acc[nt][r] + bias[idx];
        }
}

// ---------------- K3: path LayerNorm + struct K/V projection, MFMA ----------------
// 64 path-rows per block. LN: 16 lanes per row (4-shuffle chain). Coalesced uint4 output.
__global__ __launch_bounds__(256) void k_structproj(const float* __restrict__ paths,
                                                    const unsigned short* __restrict__ Wskvt, // [128][128] n-major
                                                    const float* __restrict__ gp, const float* __restrict__ bp,
                                                    const float* __restrict__ bsk, const float* __restrict__ bsv,
                                                    unsigned short* __restrict__ skv) {
    __shared__ __align__(16) unsigned short pn[64 * 136];
    __shared__ __align__(16) unsigned short Bt[128 * 136];
    int tid = threadIdx.x;
    size_t r0 = (size_t)blockIdx.x * 64;
    int w = tid >> 6, lane = tid & 63, lm = lane & 15, lq = lane >> 4;
#pragma unroll
    for (int t = 0; t < 8; t++) {  // stage Wskvt: 128x128 bf16
        int c = t * 256 + tid;
        int n = c >> 4, kc = c & 15;
        uint4 v = *(const uint4*)(Wskvt + n * 128 + kc * 8);
        *(uint4*)(Bt + n * 136 + kc * 8) = v;
    }
    // LN params for my columns (lm*4.. and 64+lm*4..)
    float4 g0 = *(const float4*)(gp + lm * 4);
    float4 g1 = *(const float4*)(gp + 64 + lm * 4);
    float4 bb0 = *(const float4*)(bp + lm * 4);
    float4 bb1 = *(const float4*)(bp + 64 + lm * 4);
#pragma unroll
    for (int it = 0; it < 4; it++) {
        int row_l = w * 16 + it * 4 + lq;          // 0..63
        size_t row = r0 + row_l;
        const float* pr = paths + row * 128;
        float4 x0 = *(const float4*)(pr + lm * 4);
        float4 x1 = *(const float4*)(pr + 64 + lm * 4);
        float s = (x0.x + x0.y) + (x0.z + x0.w) + (x1.x + x1.y) + (x1.z + x1.w);
        float s2 = x0.x * x0.x + x0.y * x0.y + x0.z * x0.z + x0.w * x0.w
                 + x1.x * x1.x + x1.y * x1.y + x1.z * x1.z + x1.w * x1.w;
#pragma unroll
        for (int mk = 1; mk < 16; mk <<= 1) {
            s += __shfl_xor(s, mk);
            s2 += __shfl_xor(s2, mk);
        }
        float mu = s * (1.f / 128.f);
        float var = s2 * (1.f / 128.f) - mu * mu;
        float rs = rsqrtf(var + EPSf);
        float p0 = (x0.x - mu) * rs * g0.x + bb0.x;
        float p1 = (x0.y - mu) * rs * g0.y + bb0.y;
        float p2 = (x0.z - mu) * rs * g0.z + bb0.z;
        float p3 = (x0.w - mu) * rs * g0.w + bb0.w;
        float p4 = (x1.x - mu) * rs * g1.x + bb1.x;
        float p5 = (x1.y - mu) * rs * g1.y + bb1.y;
        float p6 = (x1.z - mu) * rs * g1.z + bb1.z;
        float p7 = (x1.w - mu) * rs * g1.w + bb1.w;
        uint2 ua, ub;
        ua.x = (unsigned)f2bf(p0) | ((unsigned)f2bf(p1) << 16);
        ua.y = (unsigned)f2bf(p2) | ((unsigned)f2bf(p3) << 16);
        ub.x = (unsigned)f2bf(p4) | ((unsigned)f2bf(p5) << 16);
        ub.y = (unsigned)f2bf(p6) | ((unsigned)f2bf(p7) << 16);
        *(uint2*)(pn + row_l * 136 + lm * 4) = ua;
        *(uint2*)(pn + row_l * 136 + 64 + lm * 4) = ub;
    }
    __syncthreads();
    f32x4 acc[8];
#pragma unroll
    for (int i = 0; i < 8; i++) acc[i] = (f32x4){0.f, 0.f, 0.f, 0.f};
#pragma unroll
    for (int ks = 0; ks < 4; ks++) {
        bhalf8 af = *(const bhalf8*)(pn + (w * 16 + lm) * 136 + ks * 32 + lq * 8);
#pragma unroll
        for (int nt = 0; nt < 8; nt++) {
            bhalf8 bf = *(const bhalf8*)(Bt + (nt * 16 + lm) * 136 + ks * 32 + lq * 8);
            acc[nt] = __builtin_amdgcn_mfma_f32_16x16x32_bf16(af, bf, acc[nt], 0, 0, 0);
        }
    }
    __syncthreads();
    // repack output (bf16 + bias) into pn, then coalesced store
#pragma unroll
    for (int nt = 0; nt < 8; nt++) {
        int col = nt * 16 + lm;
        float bias = (col < 64) ? bsk[col] : bsv[col - 64];
#pragma unroll
        for (int r = 0; r < 4; r++) {
            int row_l = w * 16 + lq * 4 + r;
            pn[row_l * 136 + col] = f2bf(acc[nt][r] + bias);
        }
    }
    __syncthreads();
#pragma unroll
    for (int i = 0; i < 4; i++) {
        int c = i * 256 + tid;
        int row = c >> 4, chunk = c & 15;
        uint4 v = *(const uint4*)(pn + row * 136 + chunk * 8);
        *(uint4*)(skv + (r0 + row) * 128 + chunk * 8) = v;
    }
}

// ---------------- K4: per-(b,q) struct scores (MFMA) + softmax + struct-out (MFMA) ----------------
__global__ __launch_bounds__(256) void k_attn(const float* __restrict__ qs,
                                              const unsigned short* __restrict__ skv,
                                              float* __restrict__ wg,
                                              float* __restrict__ attn) {
    __shared__ __align__(16) unsigned short SKV[256 * 72];
    __shared__ __align__(16) unsigned short A2[16 * 264];
    __shared__ __align__(16) unsigned short Ql[16 * 72];
    __shared__ float redm[16][4];
    __shared__ float reds[16][4];
    int tid = threadIdx.x;
    int bq = blockIdx.x;
    int b = bq >> 8, q = bq & 255;
    int w = tid >> 6, lane = tid & 63, lm = lane & 15, lq = lane >> 4;
    // stage Q rows 0..11 (bf16), zero rows 12..15
    if (tid < 192) {
        int h = tid >> 4, dc = (tid & 15) * 4;
        float4 v = *(const float4*)(qs + (((size_t)b * HEADS + h) * Nn + q) * Dd + dc);
        uint2 u;
        u.x = (unsigned)f2bf(v.x) | ((unsigned)f2bf(v.y) << 16);
        u.y = (unsigned)f2bf(v.z) | ((unsigned)f2bf(v.w) << 16);
        *(uint2*)(Ql + h * 72 + dc) = u;
    } else {
        int t = tid - 192;
        int h = 12 + (t >> 4), dc = (t & 15) * 4;
        uint2 z; z.x = 0; z.y = 0;
        *(uint2*)(Ql + h * 72 + dc) = z;
    }
    // stage SK half: skv[bq] rows, cols 0..63
    const unsigned short* rowb = skv + (size_t)bq * 256 * 128;
#pragma unroll
    for (int i = 0; i < 8; i++) {
        int c = i * 256 + tid;
        int k = c >> 3, j = c & 7;
        uint4 v = *(const uint4*)(rowb + (size_t)k * 128 + j * 8);
        *(uint4*)(SKV + k * 72 + j * 8) = v;
    }
    __syncthreads();
    // MFMA1: S[16 h][256 k], wave w covers key tiles (w*4+nt)*16
    f32x4 acc1[4];
#pragma unroll
    for (int i = 0; i < 4; i++) acc1[i] = (f32x4){0.f, 0.f, 0.f, 0.f};
#pragma unroll
    for (int ks = 0; ks < 2; ks++) {
        bhalf8 af = *(const bhalf8*)(Ql + lm * 72 + ks * 32 + lq * 8);
#pragma unroll
        for (int nt = 0; nt < 4; nt++) {
            int n0 = (w * 4 + nt) * 16;
            bhalf8 bf = *(const bhalf8*)(SKV + (n0 + lm) * 72 + ks * 32 + lq * 8);
            acc1[nt] = __builtin_amdgcn_mfma_f32_16x16x32_bf16(af, bf, acc1[nt], 0, 0, 0);
        }
    }
    // add content scores (wg already holds qk+bias)
    size_t wbase = ((size_t)b * HEADS) * Nn * Nn + (size_t)q * Nn;
    float S[4][4];
#pragma unroll
    for (int nt = 0; nt < 4; nt++)
#pragma unroll
        for (int r = 0; r < 4; r++) {
            int row = lq * 4 + r;
            int col = (w * 4 + nt) * 16 + lm;
            float wgv = (row < 12) ? wg[wbase + (size_t)row * (Nn * Nn) + col] : 0.f;
            S[nt][r] = acc1[nt][r] + wgv;
        }
    // register softmax over 256 cols per row
    float m4[4];
#pragma unroll
    for (int r = 0; r < 4; r++)
        m4[r] = fmaxf(fmaxf(S[0][r], S[1][r]), fmaxf(S[2][r], S[3][r]));
#pragma unroll
    for (int mk = 1; mk < 16; mk <<= 1)
#pragma unroll
        for (int r = 0; r < 4; r++) m4[r] = fmaxf(m4[r], __shfl_xor(m4[r], mk));
    if (lm == 0) {
#pragma unroll
        for (int r = 0; r < 4; r++) redm[lq * 4 + r][w] = m4[r];
    }
    __syncthreads();
    float rowmax[4];
#pragma unroll
    for (int r = 0; r < 4; r++) {
        int row = lq * 4 + r;
        rowmax[r] = fmaxf(fmaxf(redm[row][0], redm[row][1]), fmaxf(redm[row][2], redm[row][3]));
    }
    float P[4][4], psum[4];
#pragma unroll
    for (int r = 0; r < 4; r++) {
#pragma unroll
        for (int nt = 0; nt < 4; nt++) P[nt][r] = __expf(S[nt][r] - rowmax[r]);
        psum[r] = (P[0][r] + P[1][r]) + (P[2][r] + P[3][r]);
    }
#pragma unroll
    for (int mk = 1; mk < 16; mk <<= 1)
#pragma unroll
        for (int r = 0; r < 4; r++) psum[r] += __shfl_xor(psum[r], mk);
    if (lm == 0) {
#pragma unroll
        for (int r = 0; r < 4; r++) reds[lq * 4 + r][w] = psum[r];
    }
    __syncthreads();
    float inv[4];
#pragma unroll
    for (int r = 0; r < 4; r++) {
        int row = lq * 4 + r;
        inv[r] = 1.f / (((reds[row][0] + reds[row][1]) + (reds[row][2] + reds[row][3])));
    }
    // write probs: bf16 into A2 (A-operand for MFMA2), fp32 back to wg for K5
#pragma unroll
    for (int nt = 0; nt < 4; nt++)
#pragma unroll
        for (int r = 0; r < 4; r++) {
            int row = lq * 4 + r;
            int col = (w * 4 + nt) * 16 + lm;
            float p = P[nt][r] * inv[r];
            A2[row * 264 + col] = f2bf(p);
            if (row < 12) wg[wbase + (size_t)row * (Nn * Nn) + col] = p;
        }
    // stage SV half into SKV (all MFMA1 reads completed before first barrier)
#pragma unroll
    for (int i = 0; i < 8; i++) {
        int c = i * 256 + tid;
        int k = c >> 3, j = c & 7;
        uint4 v = *(const uint4*)(rowb + (size_t)k * 128 + 64 + j * 8);
        *(uint4*)(SKV + k * 72 + j * 8) = v;
    }
    __syncthreads();
    // MFMA2: O[16 h][64 d] = P[16,256] @ SV[256,64]; wave w -> d-tile w*16
    f32x4 acc2 = (f32x4){0.f, 0.f, 0.f, 0.f};
#pragma unroll
    for (int ks = 0; ks < 8; ks++) {
        bhalf8 af = *(const bhalf8*)(A2 + lm * 264 + ks * 32 + lq * 8);
        bhalf8 bf;
#pragma unroll
        for (int j = 0; j < 8; j++)
            bf[j] = (short)SKV[(ks * 32 + lq * 8 + j) * 72 + w * 16 + lm];
        acc2 = __builtin_amdgcn_mfma_f32_16x16x32_bf16(af, bf, acc2, 0, 0, 0);
    }
#pragma unroll
    for (int r = 0; r < 4; r++) {
        int row = lq * 4 + r;
        if (row < 12) attn[(size_t)bq * Hh + row * 64 + w * 16 + lm] = acc2[r];
    }
}

// ---------------- K5: content out = softmax(w) @ V, accumulate into attn ----------------
__global__ __launch_bounds__(256) void k_ctxout(const float* __restrict__ wg,
                                                const float* __restrict__ vv,
                                                float* __restrict__ attn) {
    __shared__ __align__(16) float Al[64 * 68];
    __shared__ __align__(16) float Bl[64 * 68];
    int tid = threadIdx.x;
    int bh = blockIdx.y;
    int m0 = blockIdx.x * 64;
    int b = bh / 12, h = bh % 12;
    int tx = tid & 15, ty = tid >> 4;
    int c0 = tx * 4, r0 = ty * 4;
    float acc[4][4];
#pragma unroll
    for (int i = 0; i < 4; i++)
#pragma unroll
        for (int j = 0; j < 4; j++) acc[i][j] = 0.f;
    const float* Abase = wg + ((size_t)bh * Nn + m0) * Nn;
    const float* Bbase = vv + (size_t)bh * Nn * Dd;
    for (int kt = 0; kt < 256; kt += 64) {
#pragma unroll
        for (int t = 0; t < 4; t++) {
            int c = t * 256 + tid;
            int row = c >> 4, cc = c & 15;
            *(float4*)(Al + row * 68 + cc * 4) = *(const float4*)(Abase + (size_t)row * 256 + kt + cc * 4);
            *(float4*)(Bl + row * 68 + cc * 4) = *(const float4*)(Bbase + (size_t)(kt + row) * 64 + cc * 4);
        }
        __syncthreads();
#pragma unroll 8
        for (int k = 0; k < 64; k++) {
            float4 bv4 = *(const float4*)(Bl + k * 68 + c0);
            float a0 = Al[(r0 + 0) * 68 + k];
            float a1 = Al[(r0 + 1) * 68 + k];
            float a2 = Al[(r0 + 2) * 68 + k];
            float a3 = Al[(r0 + 3) * 68 + k];
            acc[0][0] += a0 * bv4.x; acc[0][1] += a0 * bv4.y; acc[0][2] += a0 * bv4.z; acc[0][3] += a0 * bv4.w;
            acc[1][0] += a1 * bv4.x; acc[1][1] += a1 * bv4.y; acc[1][2] += a1 * bv4.z; acc[1][3] += a1 * bv4.w;
            acc[2][0] += a2 * bv4.x; acc[2][1] += a2 * bv4.y; acc[2][2] += a2 * bv4.z; acc[2][3] += a2 * bv4.w;
            acc[3][0] += a3 * bv4.x; acc[3][1] += a3 * bv4.y; acc[3][2] += a3 * bv4.z; acc[3][3] += a3 * bv4.w;
        }
        __syncthreads();
    }
#pragma unroll
    for (int i = 0; i < 4; i++)
#pragma unroll
        for (int j = 0; j < 4; j++) {
            size_t o = ((size_t)b * Nn + m0 + r0 + i) * Hh + h * 64 + c0 + j;
            attn[o] += acc[i][j];
        }
}

// ---------------- K6: out projection + bias + relu + residual, MFMA ----------------
__global__ __launch_bounds__(256) void k_outproj(const float* __restrict__ attn,
                                                 const unsigned short* __restrict__ Wot, // [768][768] n-major
                                                 const float* __restrict__ bo,
                                                 const float* __restrict__ nodes,
                                                 float* __restrict__ tmp) {
    __shared__ __align__(16) unsigned short Alds[64 * 72];
    __shared__ __align__(16) unsigned short Blds[128 * 72];
    int tid = threadIdx.x;
    int m0 = blockIdx.y * 64;
    int n0 = blockIdx.x * 128;
    int w = tid >> 6, lane = tid & 63;
    int wm = w >> 1, wn = w & 1;
    int lm = lane & 15, lq = lane >> 4;
    f32x4 acc[2][4];
#pragma unroll
    for (int i = 0; i < 2; i++)
#pragma unroll
        for (int j = 0; j < 4; j++) acc[i][j] = (f32x4){0.f, 0.f, 0.f, 0.f};
    for (int kt = 0; kt < 768; kt += 64) {
#pragma unroll
        for (int t = 0; t < 4; t++) {
            int c = t * 256 + tid;
            int row = c >> 4, cc = c & 15;
            float4 v = *(const float4*)(attn + (size_t)(m0 + row) * 768 + kt + cc * 4);
            uint2 uu;
            uu.x = (unsigned)f2bf(v.x) | ((unsigned)f2bf(v.y) << 16);
            uu.y = (unsigned)f2bf(v.z) | ((unsigned)f2bf(v.w) << 16);
            *(uint2*)(Alds + row * 72 + cc * 4) = uu;
        }
#pragma unroll
        for (int t = 0; t < 4; t++) {
            int c = t * 256 + tid;
            int n = c >> 3, kc = c & 7;
            uint4 v = *(const uint4*)(Wot + (size_t)(n0 + n) * 768 + kt + kc * 8);
            *(uint4*)(Blds + n * 72 + kc * 8) = v;
        }
        __syncthreads();
#pragma unroll
        for (int ks = 0; ks < 2; ks++) {
            bhalf8 af[2];
#pragma unroll
            for (int mi = 0; mi < 2; mi++)
                af[mi] = *(const bhalf8*)(Alds + (wm * 32 + mi * 16 + lm) * 72 + ks * 32 + lq * 8);
#pragma unroll
            for (int nt = 0; nt < 4; nt++) {
                bhalf8 bf = *(const bhalf8*)(Blds + (wn * 64 + nt * 16 + lm) * 72 + ks * 32 + lq * 8);
#pragma unroll
                for (int mi = 0; mi < 2; mi++)
                    acc[mi][nt] = __builtin_amdgcn_mfma_f32_16x16x32_bf16(af[mi], bf, acc[mi][nt], 0, 0, 0);
            }
        }
        __syncthreads();
    }
#pragma unroll
    for (int mi = 0; mi < 2; mi++)
#pragma unroll
        for (int nt = 0; nt < 4; nt++)
#pragma unroll
            for (int r = 0; r < 4; r++) {
                int row = m0 + wm * 32 + mi * 16 + lq * 4 + r;
                int col = n0 + wn * 64 + nt * 16 + lm;
                float val = acc[mi][nt][r] + bo[col];
                val = fmaxf(val, 0.f) + nodes[(size_t)row * 768 + col];
                tmp[(size_t)row * 768 + col] = val;
            }
}

// ---------------- K7: final row LayerNorm ----------------
__global__ __launch_bounds__(256) void k_finalln(const float* __restrict__ tmp,
                                                 const float* __restrict__ go,
                                                 const float* __restrict__ bout,
                                                 float* __restrict__ out) {
    __shared__ float rs1[4], rs2[4];
    int m = blockIdx.x, tid = threadIdx.x;
    int lane = tid & 63, wid = tid >> 6;
    const float* row = tmp + (size_t)m * 768;
    float x0 = row[tid], x1 = row[tid + 256], x2 = row[tid + 512];
    float s = x0 + x1 + x2;
    float s2 = x0 * x0 + x1 * x1 + x2 * x2;
#pragma unroll
    for (int mk = 32; mk; mk >>= 1) {
        s += __shfl_xor(s, mk);
        s2 += __shfl_xor(s2, mk);
    }
    if (lane == 0) { rs1[wid] = s; rs2[wid] = s2; }
    __syncthreads();
    s = rs1[0] + rs1[1] + rs1[2] + rs1[3];
    s2 = rs2[0] + rs2[1] + rs2[2] + rs2[3];
    float mu = s * (1.f / 768.f);
    float var = s2 * (1.f / 768.f) - mu * mu;
    float rstd = rsqrtf(var + EPSf);
    float* orow = out + (size_t)m * 768;
    orow[tid] = (x0 - mu) * rstd * go[tid] + bout[tid];
    orow[tid + 256] = (x1 - mu) * rstd * go[tid + 256] + bout[tid + 256];
    orow[tid + 512] = (x2 - mu) * rstd * go[tid + 512] + bout[tid + 512];
}

extern "C" void kernel_launch(void* const* d_in, const int* in_sizes, int n_in,
                              void* d_out, int out_size, void* d_ws, size_t ws_size,
                              hipStream_t stream) {
    const float* nodes = (const float*)d_in[0];
    const float* bias  = (const float*)d_in[1];
    const float* paths = (const float*)d_in[2];
    const float* Wq = (const float*)d_in[3];  const float* bq  = (const float*)d_in[4];
    const float* Wk = (const float*)d_in[5];  const float* bk  = (const float*)d_in[6];
    const float* Wv = (const float*)d_in[7];  const float* bv  = (const float*)d_in[8];
    const float* Wsk = (const float*)d_in[9]; const float* bsk = (const float*)d_in[10];
    const float* Wsv = (const float*)d_in[11];const float* bsv = (const float*)d_in[12];
    const float* Wo = (const float*)d_in[13]; const float* bo  = (const float*)d_in[14];
    const float* gp = (const float*)d_in[15]; const float* bp  = (const float*)d_in[16];
    const float* go = (const float*)d_in[17]; const float* bout= (const float*)d_in[18];
    float* out = (float*)d_out;

    char* ws = (char*)d_ws;
    size_t off = 0;
    auto carve = [&](size_t bytes) -> char* {
        char* p = ws + off;
        off += (bytes + 255) & ~(size_t)255;
        return p;
    };
    float* qs   = (float*)carve((size_t)Bb * HEADS * Nn * Dd * 4);
    float* kk   = (float*)carve((size_t)Bb * HEADS * Nn * Dd * 4);
    float* vv   = (float*)carve((size_t)Bb * HEADS * Nn * Dd * 4);
    float* wg   = (float*)carve((size_t)Bb * HEADS * Nn * Nn * 4);
    float* attn = (float*)carve((size_t)Bb * Nn * Hh * 4);
    float* tmp  = (float*)carve((size_t)Bb * Nn * Hh * 4);
    unsigned short* Wqkvt = (unsigned short*)carve((size_t)3 * 768 * 768 * 2);
    unsigned short* Wot   = (unsigned short*)carve((size_t)768 * 768 * 2);
    unsigned short* Wskvt = (unsigned short*)carve((size_t)128 * 128 * 2);
    unsigned short* skv   = (unsigned short*)carve((size_t)Bb * Nn * Nn * 128 * 2);
    (void)ws_size; (void)in_sizes; (void)n_in; (void)out_size;

    // K0: weight transposes (fp32 -> bf16, n-major), merged launches
    hipLaunchKernelGGL(k_transpose4, dim3(24, 24, 4), dim3(256), 0, stream,
                       Wq, Wk, Wv, Wo,
                       Wqkvt, Wqkvt + (size_t)768 * 768, Wqkvt + (size_t)2 * 768 * 768, Wot);
    hipLaunchKernelGGL(k_transpose_small, dim3(2, 4, 2), dim3(256), 0, stream,
                       Wsk, Wsv, Wskvt, Wskvt + (size_t)64 * 128);

    // K1: QKV
    hipLaunchKernelGGL(k_qkv, dim3(18, 32), dim3(256), 0, stream, nodes, Wqkvt, bq, bk, bv, qs, kk, vv);
    // K2: content scores + bias
    hipLaunchKernelGGL(k_scores, dim3(4, 4, 96), dim3(256), 0, stream, qs, kk, bias, wg);
    // K3: path LN + struct projection
    hipLaunchKernelGGL(k_structproj, dim3(8192), dim3(256), 0, stream, paths, Wskvt, gp, bp, bsk, bsv, skv);
    // K4: struct scores + softmax + struct out (MFMA)
    hipLaunchKernelGGL(k_attn, dim3(2048), dim3(256), 0, stream, qs, skv, wg, attn);
    // K5: content out accumulate
    hipLaunchKernelGGL(k_ctxout, dim3(4, 96), dim3(256), 0, stream, wg, vv, attn);
    // K6: output projection + relu + residual
    hipLaunchKernelGGL(k_outproj, dim3(6, 32), dim3(256), 0, stream, attn, Wot, bo, nodes, tmp);
    // K7: final layernorm
    hipLaunchKernelGGL(k_finalln, dim3(2048), dim3(256), 0, stream, tmp, go, bout, out);
}